// Round 2
// baseline (261.253 us; speedup 1.0000x reference)
//
#include <hip/hip_runtime.h>

// VecLocal2d via MFMA: per-pixel GEMM  C[160 bk][64 o] = X[160][288] * W[288][64]
// x:    [160][32][32][32]  (bk, c, h, w)            fp32
// w:    [1024 pix][64 o][288 f] (f = c*9+kh*3+kw)   fp32
// bias: [10][64][32][32]                            fp32
// out:  [160][64][32][32]  (bk, o, i, j)            fp32
//
// One block per pixel (grid 1024, 512 thr = 8 waves). Stage W (bf16, [o][f])
// and im2col X (bf16, [bk][f]) in LDS; 360x mfma_f32_16x16x32_bf16.
// Row pad 296 shorts: 592 B stride = 148 dw == 20 mod 32 -> uniform 2-way
// bank aliasing (free, m136) and 16B-aligned rows for ds_read_b128.
// Weights read exactly once from HBM (the structural requirement).
// XCD-chunked swizzle: same-i / adjacent-j pixels share an XCD L2 so the
// per-XCD x slice (~3.9 MB) L2-fits and scattered out dwords merge to lines.

#define HW    32
#define CIN   32
#define COUT  64
#define FDIM  288
#define FPAD  296
#define NBK   160

using f32x4  = __attribute__((ext_vector_type(4))) float;
using bf16x8 = __attribute__((ext_vector_type(8))) short;
using s16x4  = __attribute__((ext_vector_type(4))) short;

static __device__ inline unsigned short f2bf(float f) {
    unsigned u = __float_as_uint(f);
    u += 0x7FFFu + ((u >> 16) & 1u);   // round-to-nearest-even
    return (unsigned short)(u >> 16);
}

__global__ __launch_bounds__(512) void local2d_mfma_kernel(
    const float* __restrict__ x,
    const float* __restrict__ w,
    const float* __restrict__ bias,
    float* __restrict__ out)
{
    __shared__ short Xl[NBK * FPAD];   // 94720 B
    __shared__ short Wl[COUT * FPAD];  // 37888 B   (total 132608 B, 1 blk/CU)

    const int hb  = blockIdx.x;
    const int lb  = (hb & 7) * 128 + (hb >> 3);   // XCD-chunked (1024 % 8 == 0, bijective)
    const int i   = lb >> 5;
    const int j   = lb & 31;
    const int pix = i * HW + j;
    const int tid = threadIdx.x;

    // ---- stage W: 64 o x 288 f fp32 -> bf16 LDS [o][FPAD] ----
    {
        const float* wp = w + (size_t)pix * (COUT * FDIM);
#pragma unroll
        for (int p = 0; p < 9; ++p) {               // 4608 float4 / 512 thr
            const int cc = tid + p * 512;
            const int o  = cc / 72;
            const int f4 = cc - o * 72;
            const float4 v = *reinterpret_cast<const float4*>(wp + o * FDIM + f4 * 4);
            s16x4 s;
            s.x = (short)f2bf(v.x); s.y = (short)f2bf(v.y);
            s.z = (short)f2bf(v.z); s.w = (short)f2bf(v.w);
            *reinterpret_cast<s16x4*>(&Wl[o * FPAD + f4 * 4]) = s;  // ds_write_b64, 8B-aligned
        }
    }

    // ---- stage X (im2col): Xl[bk][c*9 + kh*3 + kw] = x[bk][c][i-1+kh][j-1+kw] ----
    {
#pragma unroll
        for (int p = 0; p < 10; ++p) {              // 5120 (bk,c) tasks / 512 thr
            const int t  = tid + p * 512;
            const int bk = t >> 5;
            const int c  = t & 31;
            const float* xb = x + (size_t)bk * (CIN * HW * HW) + c * (HW * HW);
            short* dst = &Xl[bk * FPAD + c * 9];
#pragma unroll
            for (int kh = 0; kh < 3; ++kh) {
                const int ih = i - 1 + kh;
                const bool hv = (unsigned)ih < (unsigned)HW;
                const float* row = xb + ih * HW;
#pragma unroll
                for (int kw = 0; kw < 3; ++kw) {
                    const int jw = j - 1 + kw;
                    const float v = (hv && (unsigned)jw < (unsigned)HW) ? row[jw] : 0.f;
                    dst[kh * 3 + kw] = (short)f2bf(v);
                }
            }
        }
    }
    __syncthreads();

    // ---- MFMA: waves 2M x 4N; each wave 5 M-tiles x 1 N-tile x 9 K-chunks ----
    const int wave = tid >> 6;
    const int lane = tid & 63;
    const int mw   = wave >> 2;        // 0..1
    const int nw   = wave & 3;         // 0..3
    const int l15  = lane & 15;
    const int lg   = lane >> 4;        // k-chunk-of-8 within K=32

    f32x4 acc[5];
#pragma unroll
    for (int mt = 0; mt < 5; ++mt)
#pragma unroll
        for (int r = 0; r < 4; ++r) acc[mt][r] = 0.f;

    const short* brow = &Wl[(nw * 16 + l15) * FPAD + lg * 8];
    const short* arow[5];
#pragma unroll
    for (int mt = 0; mt < 5; ++mt)
        arow[mt] = &Xl[((mw * 5 + mt) * 16 + l15) * FPAD + lg * 8];

#pragma unroll
    for (int kc = 0; kc < 9; ++kc) {
        const bf16x8 b = *reinterpret_cast<const bf16x8*>(brow + kc * 32);
#pragma unroll
        for (int mt = 0; mt < 5; ++mt) {
            const bf16x8 a = *reinterpret_cast<const bf16x8*>(arow[mt] + kc * 32);
            acc[mt] = __builtin_amdgcn_mfma_f32_16x16x32_bf16(a, b, acc[mt], 0, 0, 0);
        }
    }

    // ---- epilogue: C/D map col=lane&15 -> o, row=(lane>>4)*4+r -> bk ----
    const int o = nw * 16 + l15;
#pragma unroll
    for (int mt = 0; mt < 5; ++mt) {
        const int bk0 = (mw * 5 + mt) * 16 + lg * 4;
#pragma unroll
        for (int r = 0; r < 4; ++r) {
            const int bk = bk0 + r;
            const int k  = bk % 10;                       // bk = b*10 + k
            out[(size_t)bk * (COUT * HW * HW) + (o << 10) + pix] =
                acc[mt][r] + bias[(size_t)k * (COUT * HW * HW) + (o << 10) + pix];
        }
    }
}

extern "C" void kernel_launch(void* const* d_in, const int* in_sizes, int n_in,
                              void* d_out, int out_size, void* d_ws, size_t ws_size,
                              hipStream_t stream) {
    const float* x    = (const float*)d_in[0];
    const float* w    = (const float*)d_in[1];
    const float* bias = (const float*)d_in[2];
    float* out        = (float*)d_out;

    hipLaunchKernelGGL(local2d_mfma_kernel, dim3(1024), dim3(512), 0, stream,
                       x, w, bias, out);
}

// Round 3
// 122.942 us; speedup vs baseline: 2.1250x; 2.1250x over previous
//
#include <hip/hip_runtime.h>

// VecLocal2d via MFMA, restructured to kill the staging scatter.
//
// GEMM per pixel: C[160 bk][64 o] = X[160][288] * W[288][64], K-order
// f' = (kh*3+kw)*32 + c  (c-fastest) chosen so that:
//   - A-frags (X) are contiguous 16B loads from xc[bk][h][w][c] (bf16,
//     c-fastest transform of x) -> DIRECT global->register, no X-LDS.
//   - B-frags (W) come from a 37 KB LDS tile staged fp32->bf16 with the
//     (c*9+cell) -> (cell*32+c) reorder (coalesced float4 reads).
// W is HBM-read exactly once (the structural requirement: 75.5 MB stream).
// LDS 37 KB, ~2 blocks/CU (VGPR-capped) -> cross-block stage/MFMA overlap.
// Border (kh,kw) cells: wave-uniform skip, so no halo storage in ws.

#define HW    32
#define CIN   32
#define COUT  64
#define FDIM  288
#define FPAD  296   // 592 B row: 148 dw == 20 mod 32 -> b128 reads at BW floor
#define NBK   160

using f32x4  = __attribute__((ext_vector_type(4))) float;
using bf16x8 = __attribute__((ext_vector_type(8))) short;

static __device__ inline unsigned short f2bf(float f) {
    unsigned u = __float_as_uint(f);
    u += 0x7FFFu + ((u >> 16) & 1u);   // round-to-nearest-even
    return (unsigned short)(u >> 16);
}

// ---- T1: x [bk][c][h][w] fp32  ->  xc [bk][h][w][c] bf16 ----
__global__ __launch_bounds__(256) void xpose_kernel(
    const float* __restrict__ x, short* __restrict__ xc)
{
    __shared__ short tile[HW][36];   // [w][c], pad 36 shorts (8B-aligned rows)

    const int bid = blockIdx.x;      // 5120 = bk(160) * h(32)
    const int bk  = bid >> 5;
    const int h   = bid & 31;
    const int tid = threadIdx.x;

    {   // read one (bk,h) plane: 32c x 32w, coalesced float4 over w
        const int c  = tid >> 3;
        const int w4 = (tid & 7) * 4;
        const float4 v = *reinterpret_cast<const float4*>(
            x + (size_t)(bk * 32 + c) * 1024 + h * 32 + w4);
        tile[w4 + 0][c] = (short)f2bf(v.x);
        tile[w4 + 1][c] = (short)f2bf(v.y);
        tile[w4 + 2][c] = (short)f2bf(v.z);
        tile[w4 + 3][c] = (short)f2bf(v.w);
    }
    __syncthreads();
    {   // write transposed rows, coalesced 8B per lane
        const int w  = tid >> 3;
        const int cq = tid & 7;
        const uint2 pk = *reinterpret_cast<const uint2*>(&tile[w][cq * 4]);
        *reinterpret_cast<uint2*>(
            xc + ((size_t)(bk * 1024 + h * 32 + w) * 32 + cq * 4)) = pk;
    }
}

// ---- main: per-pixel GEMM ----
__global__ __launch_bounds__(512, 4) void local2d_mfma2_kernel(
    const short* __restrict__ xc,
    const float* __restrict__ w,
    const float* __restrict__ bias,
    float* __restrict__ out)
{
    __shared__ short Wl[COUT * FPAD];   // 37888 B, layout [o][cell*32 + c]

    const int hb  = blockIdx.x;
    const int lb  = (hb & 7) * 128 + (hb >> 3);   // XCD-chunked, bijective
    const int i   = lb >> 5;
    const int j   = lb & 31;
    const int pix = i * HW + j;
    const int tid = threadIdx.x;

    // ---- stage W: fp32 [o][f=c*9+cell] -> bf16 LDS [o][f'=cell*32+c] ----
    {
        const float* wp = w + (size_t)pix * (COUT * FDIM);
#pragma unroll
        for (int p = 0; p < 9; ++p) {             // 4608 float4 / 512 thr
            const int g  = tid + p * 512;
            const int o  = g / 72;
            const int f4 = (g - o * 72) * 4;
            const float4 v = *reinterpret_cast<const float4*>(wp + o * FDIM + f4);
            const float vv[4] = {v.x, v.y, v.z, v.w};
            short* wrow = &Wl[o * FPAD];
#pragma unroll
            for (int e = 0; e < 4; ++e) {
                const int f    = f4 + e;
                const int c    = f / 9;           // magic-mul
                const int cell = f - c * 9;
                wrow[cell * 32 + c] = (short)f2bf(vv[e]);
            }
        }
    }
    __syncthreads();

    // ---- MFMA: 8 waves = 4 N-tiles x 2 M-halves; 5 mt x 9 kc each ----
    const int wave = tid >> 6;
    const int lane = tid & 63;
    const int nt   = wave & 3;
    const int mh   = wave >> 2;
    const int l15  = lane & 15;
    const int lg8  = (lane >> 4) * 8;

    f32x4 acc[5];
#pragma unroll
    for (int mt = 0; mt < 5; ++mt)
#pragma unroll
        for (int r = 0; r < 4; ++r) acc[mt][r] = 0.f;

    const short* xb[5];
#pragma unroll
    for (int mt = 0; mt < 5; ++mt) {
        const int bk = mh * 80 + mt * 16 + l15;
        xb[mt] = xc + (size_t)bk * (HW * HW * CIN) + lg8;
    }
    const short* bp = &Wl[(nt * 16 + l15) * FPAD + lg8];

#pragma unroll
    for (int kc = 0; kc < 9; ++kc) {
        const int kh = kc / 3;
        const int kw = kc - kh * 3;
        const int ih = i - 1 + kh;
        const int jw = j - 1 + kw;
        if ((unsigned)ih >= (unsigned)HW || (unsigned)jw >= (unsigned)HW)
            continue;                              // wave-uniform border skip
        const bf16x8 b = *reinterpret_cast<const bf16x8*>(bp + kc * 32);
        const int xoff = (ih * HW + jw) * CIN;     // uniform per kc
#pragma unroll
        for (int mt = 0; mt < 5; ++mt) {
            const bf16x8 a = *reinterpret_cast<const bf16x8*>(xb[mt] + xoff);
            acc[mt] = __builtin_amdgcn_mfma_f32_16x16x32_bf16(a, b, acc[mt], 0, 0, 0);
        }
    }

    // ---- epilogue: col(l&15)=o, row=(l>>4)*4+r -> bk ----
    const int o  = nt * 16 + l15;
    const int r0 = (lane >> 4) * 4;
#pragma unroll
    for (int mt = 0; mt < 5; ++mt) {
        const int bk0 = mh * 80 + mt * 16 + r0;
#pragma unroll
        for (int r = 0; r < 4; ++r) {
            const int bk = bk0 + r;
            const int k  = bk % 10;                // bk = b*10 + k
            out[((size_t)(bk * COUT + o) << 10) + pix] =
                acc[mt][r] + bias[((size_t)(k * COUT + o) << 10) + pix];
        }
    }
}

extern "C" void kernel_launch(void* const* d_in, const int* in_sizes, int n_in,
                              void* d_out, int out_size, void* d_ws, size_t ws_size,
                              hipStream_t stream) {
    const float* x    = (const float*)d_in[0];
    const float* w    = (const float*)d_in[1];
    const float* bias = (const float*)d_in[2];
    float* out        = (float*)d_out;
    short* xc         = (short*)d_ws;   // 160*32*32*32*2 B = 10.0 MB

    hipLaunchKernelGGL(xpose_kernel, dim3(5120), dim3(256), 0, stream, x, xc);
    hipLaunchKernelGGL(local2d_mfma2_kernel, dim3(1024), dim3(512), 0, stream,
                       xc, w, bias, out);
}

// Round 4
// 64.539 us; speedup vs baseline: 4.0480x; 1.9049x over previous
//
#include <hip/hip_runtime.h>

// VecLocal2d via MFMA, R4: kill the epilogue scatter + densify A-gathers.
//
// Pipeline (fast path, needs ~31.3 MB ws):
//   memset xc_halo (zeros the pad)
//   t1:   x[bk][c][h][w] fp32  ->  xc[(h+1)][(w+1)][bk][c] bf16, 34x34 halo
//   main: per-pixel GEMM C[160][64] = X[160][288] * W[288][64]
//         A-frags DIRECT from xc (fully dense 1KB/instr, branch-free kc loop)
//         W staged fp32->bf16 in 37.9KB LDS (read from HBM exactly once)
//         stores -> co[pix][o][bk] bf16 (block-contiguous, dense segments)
//   t2:   out[bk][o][pix] = f32(co[pix][o][bk]) + bias[bk%10][o][pix]
//         LDS 32x32 tile transpose, coalesced both sides
// Fallback (ws < 31.3 MB): R3 path (proven, needs 10 MB).

#define HW    32
#define CIN   32
#define COUT  64
#define FDIM  288
#define FPAD  296
#define NBK   160
#define HP    34            // halo-padded extent
#define PLANE (NBK * CIN)   // 5120 shorts per (ih,jw) plane

using f32x4  = __attribute__((ext_vector_type(4))) float;
using bf16x8 = __attribute__((ext_vector_type(8))) short;
using s16x4  = __attribute__((ext_vector_type(4))) short;

static __device__ inline unsigned short f2bf(float f) {
    unsigned u = __float_as_uint(f);
    u += 0x7FFFu + ((u >> 16) & 1u);   // round-to-nearest-even
    return (unsigned short)(u >> 16);
}
static constexpr size_t XC_BYTES = (size_t)HP * HP * PLANE * 2;       // 11,837,440
static constexpr size_t CO_BYTES = (size_t)1024 * COUT * NBK * 2;     // 20,971,520

// ---- t1: x [bk][c][h][w] fp32 -> xc [h+1][w+1][bk][c] bf16 (halo layout) ----
__global__ __launch_bounds__(256) void t1_kernel(
    const float* __restrict__ x, short* __restrict__ xc)
{
    __shared__ short tile[HW][36];
    const int bid = blockIdx.x;      // 5120 = bk(160) * h(32)
    const int bk  = bid >> 5;
    const int h   = bid & 31;
    const int tid = threadIdx.x;
    {
        const int c  = tid >> 3;
        const int w4 = (tid & 7) * 4;
        const float4 v = *reinterpret_cast<const float4*>(
            x + (size_t)(bk * 32 + c) * 1024 + h * 32 + w4);
        tile[w4 + 0][c] = (short)f2bf(v.x);
        tile[w4 + 1][c] = (short)f2bf(v.y);
        tile[w4 + 2][c] = (short)f2bf(v.z);
        tile[w4 + 3][c] = (short)f2bf(v.w);
    }
    __syncthreads();
    {
        const int w  = tid >> 3;
        const int cq = tid & 7;
        const uint2 pk = *reinterpret_cast<const uint2*>(&tile[w][cq * 4]);
        *reinterpret_cast<uint2*>(
            xc + (size_t)((h + 1) * HP + (w + 1)) * PLANE + bk * CIN + cq * 4) = pk;
    }
}

// ---- main: per-pixel GEMM, co output ----
__global__ __launch_bounds__(512, 4) void local2d_main_kernel(
    const short* __restrict__ xc,
    const float* __restrict__ w,
    short* __restrict__ co)
{
    __shared__ short Wl[COUT * FPAD];   // 37888 B, layout [o][cell*32 + c]

    const int hb  = blockIdx.x;
    const int lb  = (hb & 7) * 128 + (hb >> 3);   // XCD-chunked, bijective
    const int i   = lb >> 5;
    const int j   = lb & 31;
    const int pix = i * HW + j;
    const int tid = threadIdx.x;

    // stage W: fp32 [o][f=c*9+cell] -> bf16 LDS [o][f'=cell*32+c]
    {
        const float* wp = w + (size_t)pix * (COUT * FDIM);
#pragma unroll
        for (int p = 0; p < 9; ++p) {
            const int g  = tid + p * 512;
            const int o  = g / 72;
            const int f4 = (g - o * 72) * 4;
            const float4 v = *reinterpret_cast<const float4*>(wp + o * FDIM + f4);
            const float vv[4] = {v.x, v.y, v.z, v.w};
            short* wrow = &Wl[o * FPAD];
#pragma unroll
            for (int e = 0; e < 4; ++e) {
                const int f    = f4 + e;
                const int c    = f / 9;
                const int cell = f - c * 9;
                wrow[cell * 32 + c] = (short)f2bf(vv[e]);
            }
        }
    }
    __syncthreads();

    const int wave = tid >> 6;
    const int lane = tid & 63;
    const int nt   = wave & 3;        // N-tile (16 o)
    const int mh   = wave >> 2;       // M-half (80 bk)
    const int l15  = lane & 15;
    const int lg8  = (lane >> 4) * 8;

    f32x4 acc[5];
#pragma unroll
    for (int mt = 0; mt < 5; ++mt)
#pragma unroll
        for (int r = 0; r < 4; ++r) acc[mt][r] = 0.f;

    const short* bp = &Wl[(nt * 16 + l15) * FPAD + lg8];
    // A base: dense plane layout [ih][jw][bk][c]; branch-free (halo zeros)
    const short* ab = xc + (size_t)(i * HP + j) * PLANE
                         + (mh * 80 + l15) * CIN + lg8;

#pragma unroll
    for (int kc = 0; kc < 9; ++kc) {
        const int kh = kc / 3;
        const int kw = kc - kh * 3;
        const bf16x8 b = *reinterpret_cast<const bf16x8*>(bp + kc * 32);
        const short* ap = ab + (kh * HP + kw) * PLANE;
#pragma unroll
        for (int mt = 0; mt < 5; ++mt) {
            const bf16x8 a = *reinterpret_cast<const bf16x8*>(ap + mt * 16 * CIN);
            acc[mt] = __builtin_amdgcn_mfma_f32_16x16x32_bf16(a, b, acc[mt], 0, 0, 0);
        }
    }

    // epilogue: co[pix][o][bk] bf16; thread's 4 r-values are consecutive bk
    const int o = nt * 16 + l15;
#pragma unroll
    for (int mt = 0; mt < 5; ++mt) {
        const int bk0 = mh * 80 + mt * 16 + (lane >> 4) * 4;
        s16x4 s;
        s.x = (short)f2bf(acc[mt][0]); s.y = (short)f2bf(acc[mt][1]);
        s.z = (short)f2bf(acc[mt][2]); s.w = (short)f2bf(acc[mt][3]);
        *reinterpret_cast<s16x4*>(co + ((size_t)pix * COUT + o) * NBK + bk0) = s;
    }
}

// ---- t2: out[bk][o][pix] = f32(co[pix][o][bk]) + bias[bk%10][o][pix] ----
__global__ __launch_bounds__(256) void t2_kernel(
    const short* __restrict__ co,
    const float* __restrict__ bias,
    float* __restrict__ out)
{
    __shared__ short tl[32][36];
    const int b    = blockIdx.x;          // 10240 = o(64) * bkT(5) * pixT(32)
    const int o    = b & 63;
    const int rest = b >> 6;
    const int bkT  = rest % 5;
    const int pixT = rest / 5;
    const int tid  = threadIdx.x;
    {
        const int p  = tid >> 3;          // pix row 0..31
        const int bq = tid & 7;
        const int pix = pixT * 32 + p;
        const s16x4 v = *reinterpret_cast<const s16x4*>(
            co + ((size_t)pix * COUT + o) * NBK + bkT * 32 + bq * 4);
        *reinterpret_cast<s16x4*>(&tl[p][bq * 4]) = v;
    }
    __syncthreads();
    {
        const int bb = tid >> 3;          // bk within tile 0..31
        const int pq = tid & 7;
        const int bk = bkT * 32 + bb;
        const int k  = bk % 10;
        const size_t pbase = (size_t)pixT * 32 + pq * 4;
        const float4 bv = *reinterpret_cast<const float4*>(
            bias + ((size_t)(k * COUT + o) << 10) + pbase);
        float4 r;
        r.x = __uint_as_float(((unsigned)(unsigned short)tl[pq * 4 + 0][bb]) << 16) + bv.x;
        r.y = __uint_as_float(((unsigned)(unsigned short)tl[pq * 4 + 1][bb]) << 16) + bv.y;
        r.z = __uint_as_float(((unsigned)(unsigned short)tl[pq * 4 + 2][bb]) << 16) + bv.z;
        r.w = __uint_as_float(((unsigned)(unsigned short)tl[pq * 4 + 3][bb]) << 16) + bv.w;
        *reinterpret_cast<float4*>(out + ((size_t)(bk * COUT + o) << 10) + pbase) = r;
    }
}

// ================= R3 fallback (proven; needs 10 MB ws) =================
__global__ __launch_bounds__(256) void xpose_kernel(
    const float* __restrict__ x, short* __restrict__ xc)
{
    __shared__ short tile[HW][36];
    const int bid = blockIdx.x;
    const int bk  = bid >> 5;
    const int h   = bid & 31;
    const int tid = threadIdx.x;
    {
        const int c  = tid >> 3;
        const int w4 = (tid & 7) * 4;
        const float4 v = *reinterpret_cast<const float4*>(
            x + (size_t)(bk * 32 + c) * 1024 + h * 32 + w4);
        tile[w4 + 0][c] = (short)f2bf(v.x);
        tile[w4 + 1][c] = (short)f2bf(v.y);
        tile[w4 + 2][c] = (short)f2bf(v.z);
        tile[w4 + 3][c] = (short)f2bf(v.w);
    }
    __syncthreads();
    {
        const int w  = tid >> 3;
        const int cq = tid & 7;
        const uint2 pk = *reinterpret_cast<const uint2*>(&tile[w][cq * 4]);
        *reinterpret_cast<uint2*>(
            xc + ((size_t)(bk * 1024 + h * 32 + w) * 32 + cq * 4)) = pk;
    }
}

__global__ __launch_bounds__(512, 4) void local2d_mfma2_kernel(
    const short* __restrict__ xc,
    const float* __restrict__ w,
    const float* __restrict__ bias,
    float* __restrict__ out)
{
    __shared__ short Wl[COUT * FPAD];
    const int hb  = blockIdx.x;
    const int lb  = (hb & 7) * 128 + (hb >> 3);
    const int i   = lb >> 5;
    const int j   = lb & 31;
    const int pix = i * HW + j;
    const int tid = threadIdx.x;
    {
        const float* wp = w + (size_t)pix * (COUT * FDIM);
#pragma unroll
        for (int p = 0; p < 9; ++p) {
            const int g  = tid + p * 512;
            const int o  = g / 72;
            const int f4 = (g - o * 72) * 4;
            const float4 v = *reinterpret_cast<const float4*>(wp + o * FDIM + f4);
            const float vv[4] = {v.x, v.y, v.z, v.w};
            short* wrow = &Wl[o * FPAD];
#pragma unroll
            for (int e = 0; e < 4; ++e) {
                const int f    = f4 + e;
                const int c    = f / 9;
                const int cell = f - c * 9;
                wrow[cell * 32 + c] = (short)f2bf(vv[e]);
            }
        }
    }
    __syncthreads();
    const int wave = tid >> 6;
    const int lane = tid & 63;
    const int nt   = wave & 3;
    const int mh   = wave >> 2;
    const int l15  = lane & 15;
    const int lg8  = (lane >> 4) * 8;
    f32x4 acc[5];
#pragma unroll
    for (int mt = 0; mt < 5; ++mt)
#pragma unroll
        for (int r = 0; r < 4; ++r) acc[mt][r] = 0.f;
    const short* xb[5];
#pragma unroll
    for (int mt = 0; mt < 5; ++mt) {
        const int bk = mh * 80 + mt * 16 + l15;
        xb[mt] = xc + (size_t)bk * (HW * HW * CIN) + lg8;
    }
    const short* bp = &Wl[(nt * 16 + l15) * FPAD + lg8];
#pragma unroll
    for (int kc = 0; kc < 9; ++kc) {
        const int kh = kc / 3;
        const int kw = kc - kh * 3;
        const int ih = i - 1 + kh;
        const int jw = j - 1 + kw;
        if ((unsigned)ih >= (unsigned)HW || (unsigned)jw >= (unsigned)HW)
            continue;
        const bf16x8 b = *reinterpret_cast<const bf16x8*>(bp + kc * 32);
        const int xoff = (ih * HW + jw) * CIN;
#pragma unroll
        for (int mt = 0; mt < 5; ++mt) {
            const bf16x8 a = *reinterpret_cast<const bf16x8*>(xb[mt] + xoff);
            acc[mt] = __builtin_amdgcn_mfma_f32_16x16x32_bf16(a, b, acc[mt], 0, 0, 0);
        }
    }
    const int o  = nt * 16 + l15;
    const int r0 = (lane >> 4) * 4;
#pragma unroll
    for (int mt = 0; mt < 5; ++mt) {
        const int bk0 = mh * 80 + mt * 16 + r0;
#pragma unroll
        for (int r = 0; r < 4; ++r) {
            const int bk = bk0 + r;
            const int k  = bk % 10;
            out[((size_t)(bk * COUT + o) << 10) + pix] =
                acc[mt][r] + bias[((size_t)(k * COUT + o) << 10) + pix];
        }
    }
}

extern "C" void kernel_launch(void* const* d_in, const int* in_sizes, int n_in,
                              void* d_out, int out_size, void* d_ws, size_t ws_size,
                              hipStream_t stream) {
    const float* x    = (const float*)d_in[0];
    const float* w    = (const float*)d_in[1];
    const float* bias = (const float*)d_in[2];
    float* out        = (float*)d_out;

    if (ws_size >= XC_BYTES + CO_BYTES) {
        short* xc = (short*)d_ws;
        short* co = (short*)((char*)d_ws + XC_BYTES);
        hipMemsetAsync(xc, 0, XC_BYTES, stream);   // zero halo (memset node is capturable)
        hipLaunchKernelGGL(t1_kernel, dim3(5120), dim3(256), 0, stream, x, xc);
        hipLaunchKernelGGL(local2d_main_kernel, dim3(1024), dim3(512), 0, stream,
                           xc, w, co);
        hipLaunchKernelGGL(t2_kernel, dim3(10240), dim3(256), 0, stream,
                           co, bias, out);
    } else {
        short* xc = (short*)d_ws;                  // 10 MB, proven path
        hipLaunchKernelGGL(xpose_kernel, dim3(5120), dim3(256), 0, stream, x, xc);
        hipLaunchKernelGGL(local2d_mfma2_kernel, dim3(1024), dim3(512), 0, stream,
                           xc, w, bias, out);
    }
}

// Round 5
// 60.775 us; speedup vs baseline: 4.2987x; 1.0619x over previous
//
#include <hip/hip_runtime.h>

// VecLocal2d via MFMA, R5: register-pipelined main kernel (R4 was ILP=1,
// VGPR=32 -> serialized loads; per-wave latency chain dominated at 50us).
//
// Pipeline (fast path, needs ~31.3 MB ws):
//   hz:   zero the 132 halo planes of xc (1.3 MB, replaces 11.8 MB memset)
//   t1:   x[bk][c][h][w] fp32  ->  xc[(h+1)][(w+1)][bk][c] bf16, 34x34 halo
//   main: per-pixel GEMM C[160][64] = X[160][288] * W[288][64]
//         - W-stage: 9 float4 loads pipelined into regs, then convert+scatter
//         - A-frags: double-buffered 5-frag prefetch (next kc loads issue
//           before current kc MFMAs) -> ~5 outstanding loads/wave
//         - plain __launch_bounds__(512): let VGPRs grow (~100), 2 blocks/CU
//   t2:   out[bk][o][pix] = f32(co[pix][o][bk]) + bias[bk%10][o][pix]
// Fallback (ws < 31.3 MB): R3 path (proven, needs 10 MB).

#define HW    32
#define CIN   32
#define COUT  64
#define FDIM  288
#define FPAD  296
#define NBK   160
#define HP    34            // halo-padded extent
#define PLANE (NBK * CIN)   // 5120 shorts per (ih,jw) plane

using f32x4  = __attribute__((ext_vector_type(4))) float;
using bf16x8 = __attribute__((ext_vector_type(8))) short;
using s16x4  = __attribute__((ext_vector_type(4))) short;

static __device__ inline unsigned short f2bf(float f) {
    unsigned u = __float_as_uint(f);
    u += 0x7FFFu + ((u >> 16) & 1u);   // round-to-nearest-even
    return (unsigned short)(u >> 16);
}
static constexpr size_t XC_BYTES = (size_t)HP * HP * PLANE * 2;       // 11,837,440
static constexpr size_t CO_BYTES = (size_t)1024 * COUT * NBK * 2;     // 20,971,520

// ---- hz: zero the 132 halo planes (h=0, h=33, and w in {0,33}) ----
__global__ __launch_bounds__(256) void hz_kernel(short* __restrict__ xc)
{
    const int id = blockIdx.x;           // 0..131
    int h, w;
    if (id < 34)      { h = 0;  w = id; }
    else if (id < 68) { h = 33; w = id - 34; }
    else { const int e = id - 68; h = 1 + (e >> 1); w = (e & 1) * 33; }
    uint2* p = reinterpret_cast<uint2*>(xc + (size_t)(h * HP + w) * PLANE);
    const uint2 z = {0u, 0u};
#pragma unroll
    for (int r = 0; r < 5; ++r)          // 1280 uint2 per plane / 256 thr
        p[threadIdx.x + r * 256] = z;
}

// ---- t1: x [bk][c][h][w] fp32 -> xc [h+1][w+1][bk][c] bf16 (halo layout) ----
__global__ __launch_bounds__(256) void t1_kernel(
    const float* __restrict__ x, short* __restrict__ xc)
{
    __shared__ short tile[HW][36];
    const int bid = blockIdx.x;      // 5120 = bk(160) * h(32)
    const int bk  = bid >> 5;
    const int h   = bid & 31;
    const int tid = threadIdx.x;
    {
        const int c  = tid >> 3;
        const int w4 = (tid & 7) * 4;
        const float4 v = *reinterpret_cast<const float4*>(
            x + (size_t)(bk * 32 + c) * 1024 + h * 32 + w4);
        tile[w4 + 0][c] = (short)f2bf(v.x);
        tile[w4 + 1][c] = (short)f2bf(v.y);
        tile[w4 + 2][c] = (short)f2bf(v.z);
        tile[w4 + 3][c] = (short)f2bf(v.w);
    }
    __syncthreads();
    {
        const int w  = tid >> 3;
        const int cq = tid & 7;
        const uint2 pk = *reinterpret_cast<const uint2*>(&tile[w][cq * 4]);
        *reinterpret_cast<uint2*>(
            xc + (size_t)((h + 1) * HP + (w + 1)) * PLANE + bk * CIN + cq * 4) = pk;
    }
}

// ---- main: per-pixel GEMM, co output ----
__global__ __launch_bounds__(512) void local2d_main_kernel(
    const short* __restrict__ xc,
    const float* __restrict__ w,
    short* __restrict__ co)
{
    __shared__ short Wl[COUT * FPAD];   // 37888 B, layout [o][cell*32 + c]

    const int hb  = blockIdx.x;
    const int lb  = (hb & 7) * 128 + (hb >> 3);   // XCD-chunked, bijective
    const int i   = lb >> 5;
    const int j   = lb & 31;
    const int pix = i * HW + j;
    const int tid = threadIdx.x;

    // ---- stage W: pipelined 9x float4 load, then convert + scatter ----
    {
        const float* wp = w + (size_t)pix * (COUT * FDIM);
        float4 wv[9];                    // static-indexed (full unroll)
#pragma unroll
        for (int p = 0; p < 9; ++p) {
            const int g  = tid + p * 512;
            const int o  = g / 72;
            const int f4 = (g - o * 72) * 4;
            wv[p] = *reinterpret_cast<const float4*>(wp + o * FDIM + f4);
        }
#pragma unroll
        for (int p = 0; p < 9; ++p) {
            const int g  = tid + p * 512;
            const int o  = g / 72;
            const int f4 = (g - o * 72) * 4;
            const float vv[4] = {wv[p].x, wv[p].y, wv[p].z, wv[p].w};
            short* wrow = &Wl[o * FPAD];
#pragma unroll
            for (int e = 0; e < 4; ++e) {
                const int f    = f4 + e;
                const int c    = f / 9;
                const int cell = f - c * 9;
                wrow[cell * 32 + c] = (short)f2bf(vv[e]);
            }
        }
    }
    __syncthreads();

    const int wave = tid >> 6;
    const int lane = tid & 63;
    const int nt   = wave & 3;        // N-tile (16 o)
    const int mh   = wave >> 2;       // M-half (80 bk)
    const int l15  = lane & 15;
    const int lg8  = (lane >> 4) * 8;

    f32x4 acc[5];
#pragma unroll
    for (int mt = 0; mt < 5; ++mt)
#pragma unroll
        for (int r = 0; r < 4; ++r) acc[mt][r] = 0.f;

    const short* bp = &Wl[(nt * 16 + l15) * FPAD + lg8];
    const short* ab = xc + (size_t)(i * HP + j) * PLANE
                         + (mh * 80 + l15) * CIN + lg8;

    // ---- kc loop, double-buffered A prefetch (all indices static) ----
    bf16x8 abuf[2][5];
#pragma unroll
    for (int mt = 0; mt < 5; ++mt)
        abuf[0][mt] = *reinterpret_cast<const bf16x8*>(ab + mt * 16 * CIN);

#pragma unroll
    for (int kc = 0; kc < 9; ++kc) {
        const int cur = kc & 1;
        if (kc < 8) {
            const int kn  = kc + 1;
            const int off = ((kn / 3) * HP + (kn % 3)) * PLANE;
#pragma unroll
            for (int mt = 0; mt < 5; ++mt)
                abuf[cur ^ 1][mt] =
                    *reinterpret_cast<const bf16x8*>(ab + off + mt * 16 * CIN);
        }
        const bf16x8 b = *reinterpret_cast<const bf16x8*>(bp + kc * 32);
#pragma unroll
        for (int mt = 0; mt < 5; ++mt)
            acc[mt] = __builtin_amdgcn_mfma_f32_16x16x32_bf16(
                abuf[cur][mt], b, acc[mt], 0, 0, 0);
    }

    // ---- epilogue: co[pix][o][bk] bf16 (dense per-wave segments) ----
    const int o = nt * 16 + l15;
#pragma unroll
    for (int mt = 0; mt < 5; ++mt) {
        const int bk0 = mh * 80 + mt * 16 + (lane >> 4) * 4;
        s16x4 s;
        s.x = (short)f2bf(acc[mt][0]); s.y = (short)f2bf(acc[mt][1]);
        s.z = (short)f2bf(acc[mt][2]); s.w = (short)f2bf(acc[mt][3]);
        *reinterpret_cast<s16x4*>(co + ((size_t)pix * COUT + o) * NBK + bk0) = s;
    }
}

// ---- t2: out[bk][o][pix] = f32(co[pix][o][bk]) + bias[bk%10][o][pix] ----
__global__ __launch_bounds__(256) void t2_kernel(
    const short* __restrict__ co,
    const float* __restrict__ bias,
    float* __restrict__ out)
{
    __shared__ short tl[32][36];
    const int b    = blockIdx.x;          // 10240 = o(64) * bkT(5) * pixT(32)
    const int o    = b & 63;
    const int rest = b >> 6;
    const int bkT  = rest % 5;
    const int pixT = rest / 5;
    const int tid  = threadIdx.x;
    {
        const int p  = tid >> 3;
        const int bq = tid & 7;
        const int pix = pixT * 32 + p;
        const s16x4 v = *reinterpret_cast<const s16x4*>(
            co + ((size_t)pix * COUT + o) * NBK + bkT * 32 + bq * 4);
        *reinterpret_cast<s16x4*>(&tl[p][bq * 4]) = v;
    }
    __syncthreads();
    {
        const int bb = tid >> 3;
        const int pq = tid & 7;
        const int bk = bkT * 32 + bb;
        const int k  = bk % 10;
        const size_t pbase = (size_t)pixT * 32 + pq * 4;
        const float4 bv = *reinterpret_cast<const float4*>(
            bias + ((size_t)(k * COUT + o) << 10) + pbase);
        float4 r;
        r.x = __uint_as_float(((unsigned)(unsigned short)tl[pq * 4 + 0][bb]) << 16) + bv.x;
        r.y = __uint_as_float(((unsigned)(unsigned short)tl[pq * 4 + 1][bb]) << 16) + bv.y;
        r.z = __uint_as_float(((unsigned)(unsigned short)tl[pq * 4 + 2][bb]) << 16) + bv.z;
        r.w = __uint_as_float(((unsigned)(unsigned short)tl[pq * 4 + 3][bb]) << 16) + bv.w;
        *reinterpret_cast<float4*>(out + ((size_t)(bk * COUT + o) << 10) + pbase) = r;
    }
}

// ================= R3 fallback (proven; needs 10 MB ws) =================
__global__ __launch_bounds__(256) void xpose_kernel(
    const float* __restrict__ x, short* __restrict__ xc)
{
    __shared__ short tile[HW][36];
    const int bid = blockIdx.x;
    const int bk  = bid >> 5;
    const int h   = bid & 31;
    const int tid = threadIdx.x;
    {
        const int c  = tid >> 3;
        const int w4 = (tid & 7) * 4;
        const float4 v = *reinterpret_cast<const float4*>(
            x + (size_t)(bk * 32 + c) * 1024 + h * 32 + w4);
        tile[w4 + 0][c] = (short)f2bf(v.x);
        tile[w4 + 1][c] = (short)f2bf(v.y);
        tile[w4 + 2][c] = (short)f2bf(v.z);
        tile[w4 + 3][c] = (short)f2bf(v.w);
    }
    __syncthreads();
    {
        const int w  = tid >> 3;
        const int cq = tid & 7;
        const uint2 pk = *reinterpret_cast<const uint2*>(&tile[w][cq * 4]);
        *reinterpret_cast<uint2*>(
            xc + ((size_t)(bk * 1024 + h * 32 + w) * 32 + cq * 4)) = pk;
    }
}

__global__ __launch_bounds__(512, 4) void local2d_mfma2_kernel(
    const short* __restrict__ xc,
    const float* __restrict__ w,
    const float* __restrict__ bias,
    float* __restrict__ out)
{
    __shared__ short Wl[COUT * FPAD];
    const int hb  = blockIdx.x;
    const int lb  = (hb & 7) * 128 + (hb >> 3);
    const int i   = lb >> 5;
    const int j   = lb & 31;
    const int pix = i * HW + j;
    const int tid = threadIdx.x;
    {
        const float* wp = w + (size_t)pix * (COUT * FDIM);
#pragma unroll
        for (int p = 0; p < 9; ++p) {
            const int g  = tid + p * 512;
            const int o  = g / 72;
            const int f4 = (g - o * 72) * 4;
            const float4 v = *reinterpret_cast<const float4*>(wp + o * FDIM + f4);
            const float vv[4] = {v.x, v.y, v.z, v.w};
            short* wrow = &Wl[o * FPAD];
#pragma unroll
            for (int e = 0; e < 4; ++e) {
                const int f    = f4 + e;
                const int c    = f / 9;
                const int cell = f - c * 9;
                wrow[cell * 32 + c] = (short)f2bf(vv[e]);
            }
        }
    }
    __syncthreads();
    const int wave = tid >> 6;
    const int lane = tid & 63;
    const int nt   = wave & 3;
    const int mh   = wave >> 2;
    const int l15  = lane & 15;
    const int lg8  = (lane >> 4) * 8;
    f32x4 acc[5];
#pragma unroll
    for (int mt = 0; mt < 5; ++mt)
#pragma unroll
        for (int r = 0; r < 4; ++r) acc[mt][r] = 0.f;
    const short* xb[5];
#pragma unroll
    for (int mt = 0; mt < 5; ++mt) {
        const int bk = mh * 80 + mt * 16 + l15;
        xb[mt] = xc + (size_t)bk * (HW * HW * CIN) + lg8;
    }
    const short* bp = &Wl[(nt * 16 + l15) * FPAD + lg8];
#pragma unroll
    for (int kc = 0; kc < 9; ++kc) {
        const int kh = kc / 3;
        const int kw = kc - kh * 3;
        const int ih = i - 1 + kh;
        const int jw = j - 1 + kw;
        if ((unsigned)ih >= (unsigned)HW || (unsigned)jw >= (unsigned)HW)
            continue;
        const bf16x8 b = *reinterpret_cast<const bf16x8*>(bp + kc * 32);
        const int xoff = (ih * HW + jw) * CIN;
#pragma unroll
        for (int mt = 0; mt < 5; ++mt) {
            const bf16x8 a = *reinterpret_cast<const bf16x8*>(xb[mt] + xoff);
            acc[mt] = __builtin_amdgcn_mfma_f32_16x16x32_bf16(a, b, acc[mt], 0, 0, 0);
        }
    }
    const int o  = nt * 16 + l15;
    const int r0 = (lane >> 4) * 4;
#pragma unroll
    for (int mt = 0; mt < 5; ++mt) {
        const int bk0 = mh * 80 + mt * 16 + r0;
#pragma unroll
        for (int r = 0; r < 4; ++r) {
            const int bk = bk0 + r;
            const int k  = bk % 10;
            out[((size_t)(bk * COUT + o) << 10) + pix] =
                acc[mt][r] + bias[((size_t)(k * COUT + o) << 10) + pix];
        }
    }
}

extern "C" void kernel_launch(void* const* d_in, const int* in_sizes, int n_in,
                              void* d_out, int out_size, void* d_ws, size_t ws_size,
                              hipStream_t stream) {
    const float* x    = (const float*)d_in[0];
    const float* w    = (const float*)d_in[1];
    const float* bias = (const float*)d_in[2];
    float* out        = (float*)d_out;

    if (ws_size >= XC_BYTES + CO_BYTES) {
        short* xc = (short*)d_ws;
        short* co = (short*)((char*)d_ws + XC_BYTES);
        hipLaunchKernelGGL(hz_kernel, dim3(132), dim3(256), 0, stream, xc);
        hipLaunchKernelGGL(t1_kernel, dim3(5120), dim3(256), 0, stream, x, xc);
        hipLaunchKernelGGL(local2d_main_kernel, dim3(1024), dim3(512), 0, stream,
                           xc, w, co);
        hipLaunchKernelGGL(t2_kernel, dim3(10240), dim3(256), 0, stream,
                           co, bias, out);
    } else {
        short* xc = (short*)d_ws;                  // 10 MB, proven path
        hipLaunchKernelGGL(xpose_kernel, dim3(5120), dim3(256), 0, stream, x, xc);
        hipLaunchKernelGGL(local2d_mfma2_kernel, dim3(1024), dim3(512), 0, stream,
                           xc, w, bias, out);
    }
}